// Round 1
// baseline (366.083 us; speedup 1.0000x reference)
//
#include <hip/hip_runtime.h>
#include <hip/hip_bf16.h>
#include <cstdint>

// MoE SwiGLU: E=8 experts, top-2, D=1024, H=2048, T=4096 tokens.
// Sparse (gathered) bf16 MFMA evaluation. ~137 MB workspace required.

#define E_ 8
#define D_ 1024
#define H_ 2048
#define T_ 4096

typedef __attribute__((ext_vector_type(8))) __bf16 bf16x8;
typedef __attribute__((ext_vector_type(4))) float f32x4;
typedef unsigned short u16;

__device__ __forceinline__ u16 f2b(float f) {
    union { float f; unsigned int u; } v; v.f = f;
    unsigned int u = v.u;
    return (u16)((u + 0x7FFFu + ((u >> 16) & 1u)) >> 16);  // RNE
}

__device__ __forceinline__ void gld16(const void* g, void* l) {
    __builtin_amdgcn_global_load_lds((const __attribute__((address_space(1))) void*)g,
                                     (__attribute__((address_space(3))) void*)l, 16, 0, 0);
}

// ---- x fp32 -> bf16 ----
__global__ void k_cvt_x(const float* __restrict__ in, u16* __restrict__ out) {
    int i = (blockIdx.x * 256 + threadIdx.x) * 4;
    float4 v = *(const float4*)(in + i);
    unsigned long long p = (unsigned long long)f2b(v.x)
                         | ((unsigned long long)f2b(v.y) << 16)
                         | ((unsigned long long)f2b(v.z) << 32)
                         | ((unsigned long long)f2b(v.w) << 48);
    *(unsigned long long*)(out + i) = p;
}

// ---- per-expert transpose fp32 [R][C] -> bf16 [C][R] ----
__global__ void k_transpose_cvt(const float* __restrict__ in, u16* __restrict__ out,
                                int R, int C) {
    __shared__ float tile[32][33];
    int z = blockIdx.z;
    const float* src = in + (size_t)z * R * C;
    u16* dst = out + (size_t)z * R * C;
    int c0 = blockIdx.x * 32, r0 = blockIdx.y * 32;
    int tc = threadIdx.x & 31, tr = threadIdx.x >> 5;  // tr 0..7
#pragma unroll
    for (int i = 0; i < 4; ++i)
        tile[tr + 8 * i][tc] = src[(size_t)(r0 + tr + 8 * i) * C + c0 + tc];
    __syncthreads();
#pragma unroll
    for (int i = 0; i < 4; ++i)
        dst[(size_t)(c0 + tr + 8 * i) * R + r0 + tc] = f2b(tile[tc][tr + 8 * i]);
}

// ---- gate: logits, top-2, softmax, per-expert token lists ----
__global__ void k_gate(const float* __restrict__ x, const float* __restrict__ gw,
                       int* __restrict__ cnt, int* __restrict__ tok,
                       float* __restrict__ wgt) {
    int wid = threadIdx.x >> 6, lane = threadIdx.x & 63;
    int t = blockIdx.x * 4 + wid;
    float part[E_];
#pragma unroll
    for (int e = 0; e < E_; ++e) part[e] = 0.f;
    const float* xr = x + (size_t)t * D_;
    for (int i = 0; i < D_ / 64; ++i) {
        float xv = xr[i * 64 + lane];
#pragma unroll
        for (int e = 0; e < E_; ++e) part[e] += xv * gw[e * D_ + i * 64 + lane];
    }
#pragma unroll
    for (int off = 32; off >= 1; off >>= 1) {
#pragma unroll
        for (int e = 0; e < E_; ++e) part[e] += __shfl_xor(part[e], off);
    }
    if (lane == 0) {
        int e0 = 0; float m0 = part[0];
#pragma unroll
        for (int e = 1; e < E_; ++e) if (part[e] > m0) { m0 = part[e]; e0 = e; }
        int e1 = -1; float m1 = -3.4e38f;
#pragma unroll
        for (int e = 0; e < E_; ++e) if (e != e0 && part[e] > m1) { m1 = part[e]; e1 = e; }
        float s = __expf(m1 - m0);
        float w0 = 1.f / (1.f + s);
        float w1 = s / (1.f + s);
        int p0 = atomicAdd(&cnt[e0], 1);
        tok[e0 * T_ + p0] = t; wgt[e0 * T_ + p0] = w0;
        int p1 = atomicAdd(&cnt[e1], 1);
        tok[e1 * T_ + p1] = t; wgt[e1 * T_ + p1] = w1;
    }
}

__global__ void k_scan(const int* __restrict__ cnt, int* __restrict__ offs) {
    if (threadIdx.x == 0) {
        int a = 0;
        for (int e = 0; e < E_; ++e) { offs[e] = a; a += cnt[e]; }
    }
}

// ---- GEMM1: gathered X[rows,1024] @ {W0t,W1t}[64-col tile] -> g = h0*silu(h1), bf16 ----
// block 256 = 4 waves (2x2), tile BM=128 x BN=64(per weight), BK=64
__launch_bounds__(256, 2)
__global__ void k_gemm1(const u16* __restrict__ xb, const u16* __restrict__ w0t,
                        const u16* __restrict__ w1t, const float* __restrict__ b0,
                        const float* __restrict__ b1, const int* __restrict__ tok,
                        const int* __restrict__ cnt, const int* __restrict__ offs,
                        u16* __restrict__ gbuf) {
    int e = blockIdx.z, rt = blockIdx.y, ct = blockIdx.x;
    int cN = cnt[e];
    if (rt * 128 >= cN) return;
    __shared__ u16 lds[16384];  // A:[128][64] @0, B0:[64][64] @16KB, B1 @24KB (bytes)
    char* ldsB = (char*)lds;
    int tid = threadIdx.x, wid = tid >> 6, lane = tid & 63;
    int wm = wid >> 1, wn = wid & 1;
    const int* tokE = tok + e * T_;
    const u16* w0e = w0t + (size_t)e * H_ * D_;
    const u16* w1e = w1t + (size_t)e * H_ * D_;

    size_t aoff[4]; int adst[4];
#pragma unroll
    for (int p = 0; p < 4; ++p) {
        int cid = p * 256 + tid, r = cid >> 3, c = cid & 7;
        int cc = c ^ (r & 7);                       // pre-swizzled source chunk
        int tk = tokE[min(rt * 128 + r, cN - 1)];   // gather (clamped padding)
        aoff[p] = (size_t)tk * D_ + cc * 8;
        adst[p] = (p * 256 + wid * 64) * 16;
    }
    size_t boff[2]; int bdst[2];
#pragma unroll
    for (int p = 0; p < 2; ++p) {
        int cid = p * 256 + tid, n = cid >> 3, c = cid & 7;
        int cc = c ^ (n & 7);
        boff[p] = (size_t)(ct * 64 + n) * D_ + cc * 8;
        bdst[p] = (p * 256 + wid * 64) * 16;
    }

    f32x4 acc0[4][2], acc1[4][2];
#pragma unroll
    for (int m = 0; m < 4; ++m)
#pragma unroll
        for (int n = 0; n < 2; ++n) { acc0[m][n] = (f32x4)0.f; acc1[m][n] = (f32x4)0.f; }

    for (int kt = 0; kt < D_ / 64; ++kt) {
        int k0 = kt * 64;
        __syncthreads();
#pragma unroll
        for (int p = 0; p < 4; ++p) gld16(xb + aoff[p] + k0, ldsB + adst[p]);
#pragma unroll
        for (int p = 0; p < 2; ++p) gld16(w0e + boff[p] + k0, ldsB + 16384 + bdst[p]);
#pragma unroll
        for (int p = 0; p < 2; ++p) gld16(w1e + boff[p] + k0, ldsB + 24576 + bdst[p]);
        __syncthreads();
#pragma unroll
        for (int ks = 0; ks < 2; ++ks) {
            int kc = ks * 4 + (lane >> 4);
            bf16x8 af[4], b0f[2], b1f[2];
#pragma unroll
            for (int m = 0; m < 4; ++m) {
                int row = wm * 64 + m * 16 + (lane & 15);
                af[m] = *(const bf16x8*)(ldsB + row * 128 + ((kc ^ (row & 7)) << 4));
            }
#pragma unroll
            for (int n = 0; n < 2; ++n) {
                int nr = wn * 32 + n * 16 + (lane & 15);
                int so = (kc ^ (nr & 7)) << 4;
                b0f[n] = *(const bf16x8*)(ldsB + 16384 + nr * 128 + so);
                b1f[n] = *(const bf16x8*)(ldsB + 24576 + nr * 128 + so);
            }
#pragma unroll
            for (int m = 0; m < 4; ++m)
#pragma unroll
                for (int n = 0; n < 2; ++n) {
                    acc0[m][n] = __builtin_amdgcn_mfma_f32_16x16x32_bf16(af[m], b0f[n], acc0[m][n], 0, 0, 0);
                    acc1[m][n] = __builtin_amdgcn_mfma_f32_16x16x32_bf16(af[m], b1f[n], acc1[m][n], 0, 0, 0);
                }
        }
    }
    int off_e = offs[e];
    const float* b0e = b0 + e * H_;
    const float* b1e = b1 + e * H_;
#pragma unroll
    for (int n = 0; n < 2; ++n) {
        int hc = ct * 64 + wn * 32 + n * 16 + (lane & 15);
        float bb0 = b0e[hc], bb1 = b1e[hc];
#pragma unroll
        for (int m = 0; m < 4; ++m)
#pragma unroll
            for (int i = 0; i < 4; ++i) {
                int row = wm * 64 + m * 16 + (lane >> 4) * 4 + i;
                int idx = rt * 128 + row;
                if (idx < cN) {
                    float h0 = acc0[m][n][i] + bb0;
                    float h1 = acc1[m][n][i] + bb1;
                    float g = h0 * h1 / (1.f + __expf(-h1));
                    gbuf[(size_t)(off_e + idx) * H_ + hc] = f2b(g);
                }
            }
    }
}

// ---- GEMM2: g[rows,2048] @ W2t[128-col tile] -> scaled atomicAdd into out ----
__launch_bounds__(256, 2)
__global__ void k_gemm2(const u16* __restrict__ gbuf, const u16* __restrict__ w2t,
                        const float* __restrict__ b2, const int* __restrict__ tok,
                        const float* __restrict__ wgt, const int* __restrict__ cnt,
                        const int* __restrict__ offs, float* __restrict__ out) {
    int e = blockIdx.z, rt = blockIdx.y, ct = blockIdx.x;
    int cN = cnt[e];
    if (rt * 128 >= cN) return;
    __shared__ u16 lds[16384];  // A:[128][64] @0, B:[128][64] @16KB (bytes)
    char* ldsB = (char*)lds;
    int tid = threadIdx.x, wid = tid >> 6, lane = tid & 63;
    int wm = wid >> 1, wn = wid & 1;
    int off_e = offs[e];
    const u16* Ag = gbuf + (size_t)(off_e + rt * 128) * H_;
    const u16* Bw = w2t + (size_t)e * D_ * H_ + (size_t)(ct * 128) * H_;

    size_t soff[4]; int sdst[4];
#pragma unroll
    for (int p = 0; p < 4; ++p) {
        int cid = p * 256 + tid, r = cid >> 3, c = cid & 7;
        int cc = c ^ (r & 7);
        soff[p] = (size_t)r * H_ + cc * 8;
        sdst[p] = (p * 256 + wid * 64) * 16;
    }
    f32x4 acc[4][4];
#pragma unroll
    for (int m = 0; m < 4; ++m)
#pragma unroll
        for (int n = 0; n < 4; ++n) acc[m][n] = (f32x4)0.f;

    for (int kt = 0; kt < H_ / 64; ++kt) {
        int k0 = kt * 64;
        __syncthreads();
#pragma unroll
        for (int p = 0; p < 4; ++p) gld16(Ag + soff[p] + k0, ldsB + sdst[p]);
#pragma unroll
        for (int p = 0; p < 4; ++p) gld16(Bw + soff[p] + k0, ldsB + 16384 + sdst[p]);
        __syncthreads();
#pragma unroll
        for (int ks = 0; ks < 2; ++ks) {
            int kc = ks * 4 + (lane >> 4);
            bf16x8 af[4], bfr[4];
#pragma unroll
            for (int m = 0; m < 4; ++m) {
                int row = wm * 64 + m * 16 + (lane & 15);
                af[m] = *(const bf16x8*)(ldsB + row * 128 + ((kc ^ (row & 7)) << 4));
            }
#pragma unroll
            for (int n = 0; n < 4; ++n) {
                int nr = wn * 64 + n * 16 + (lane & 15);
                bfr[n] = *(const bf16x8*)(ldsB + 16384 + nr * 128 + ((kc ^ (nr & 7)) << 4));
            }
#pragma unroll
            for (int m = 0; m < 4; ++m)
#pragma unroll
                for (int n = 0; n < 4; ++n)
                    acc[m][n] = __builtin_amdgcn_mfma_f32_16x16x32_bf16(af[m], bfr[n], acc[m][n], 0, 0, 0);
        }
    }
    const int* tokE = tok + e * T_;
    const float* wgtE = wgt + e * T_;
    const float* b2e = b2 + e * D_;
#pragma unroll
    for (int m = 0; m < 4; ++m)
#pragma unroll
        for (int i = 0; i < 4; ++i) {
            int row = wm * 64 + m * 16 + (lane >> 4) * 4 + i;
            int idx = rt * 128 + row;
            if (idx < cN) {
                int t = tokE[idx];
                float w = wgtE[idx];
#pragma unroll
                for (int n = 0; n < 4; ++n) {
                    int dc = ct * 128 + wn * 64 + n * 16 + (lane & 15);
                    float val = acc[m][n][i] + b2e[dc];
                    atomicAdd(out + (size_t)t * D_ + dc, w * val);
                }
            }
        }
}

extern "C" void kernel_launch(void* const* d_in, const int* in_sizes, int n_in,
                              void* d_out, int out_size, void* d_ws, size_t ws_size,
                              hipStream_t stream) {
    const float* x  = (const float*)d_in[0];
    const float* gw = (const float*)d_in[1];
    const float* W0 = (const float*)d_in[2];
    const float* b0 = (const float*)d_in[3];
    const float* W1 = (const float*)d_in[4];
    const float* b1 = (const float*)d_in[5];
    const float* W2 = (const float*)d_in[6];
    const float* b2 = (const float*)d_in[7];
    float* out = (float*)d_out;

    char* ws = (char*)d_ws;
    size_t off = 0;
    u16* xb   = (u16*)(ws + off); off += (size_t)T_ * D_ * 2;        // 8 MB
    u16* w0t  = (u16*)(ws + off); off += (size_t)E_ * H_ * D_ * 2;   // 32 MB
    u16* w1t  = (u16*)(ws + off); off += (size_t)E_ * H_ * D_ * 2;   // 32 MB
    u16* w2t  = (u16*)(ws + off); off += (size_t)E_ * D_ * H_ * 2;   // 32 MB
    u16* gbuf = (u16*)(ws + off); off += (size_t)(T_ * 2 + 128) * H_ * 2; // 32.5 MB
    int*   tok  = (int*)(ws + off);   off += (size_t)E_ * T_ * 4;
    float* wgt  = (float*)(ws + off); off += (size_t)E_ * T_ * 4;
    int*   cnt  = (int*)(ws + off);   off += 64;
    int*   offs = (int*)(ws + off);   off += 64;

    hipMemsetAsync(d_out, 0, (size_t)out_size * 4, stream);
    if (ws_size < off) return;  // workspace too small: leave zeros (visible failure)
    hipMemsetAsync(cnt, 0, 64, stream);

    k_cvt_x<<<T_ * D_ / 1024, 256, 0, stream>>>(x, xb);
    k_transpose_cvt<<<dim3(H_ / 32, D_ / 32, E_), 256, 0, stream>>>(W0, w0t, D_, H_);
    k_transpose_cvt<<<dim3(H_ / 32, D_ / 32, E_), 256, 0, stream>>>(W1, w1t, D_, H_);
    k_transpose_cvt<<<dim3(D_ / 32, H_ / 32, E_), 256, 0, stream>>>(W2, w2t, H_, D_);
    k_gate<<<T_ / 4, 256, 0, stream>>>(x, gw, cnt, tok, wgt);
    k_scan<<<1, 64, 0, stream>>>(cnt, offs);
    k_gemm1<<<dim3(H_ / 64, T_ / 128, E_), 256, 0, stream>>>(xb, w0t, w1t, b0, b1, tok, cnt, offs, gbuf);
    k_gemm2<<<dim3(D_ / 128, T_ / 128, E_), 256, 0, stream>>>(gbuf, w2t, b2, tok, wgt, cnt, offs, out);
}